// Round 6
// baseline (219.350 us; speedup 1.0000x reference)
//
#include <hip/hip_runtime.h>
#include <hip/hip_bf16.h>

// NVFP4 dynamic linear: x[2,2048,4096] f32, w[4096,4096] f32, bias[4096] -> out f32
// M=4096, N=4096, K=4096.
//
// amax -> quant/dequant to bf16 (exact: e2m1 code x e4m3 scale fits bf16;
// products accumulate exactly in fp32 MFMA) -> 256x256 bf16 MFMA GEMM.
// GEMM: ring-4 LDS (BK=32), ONE barrier segment per K-tile, ds_read/MFMA
// interleaved at row granularity (AITER pattern) and pinned with
// sched_group_barrier so each row's LDS serve hides under the previous
// row's MFMA. Counted vmcnt(10) once per tile. T1 XCD swizzle, T2 LDS
// swizzle, T5 setprio, T19 sched_group_barrier.
//
// ws: [0,8) amax bits | [256, +32MB) dx bf16 | [+32MB) dw bf16

typedef unsigned short u16;
typedef __bf16 bf16x8 __attribute__((ext_vector_type(8)));
typedef float f32x4 __attribute__((ext_vector_type(4)));
typedef unsigned short u16x8 __attribute__((ext_vector_type(8)));

#define GLD_LDS(gsrc, ldst)                                                     \
  __builtin_amdgcn_global_load_lds(                                             \
      (const __attribute__((address_space(1))) void*)(gsrc),                    \
      (__attribute__((address_space(3))) void*)(ldst), 16, 0, 0)

#define SBAR()                                                                  \
  do {                                                                          \
    asm volatile("" ::: "memory");                                              \
    __builtin_amdgcn_s_barrier();                                               \
    asm volatile("" ::: "memory");                                              \
  } while (0)

#define VMCNT_(N) asm volatile("s_waitcnt vmcnt(" #N ")" ::: "memory")
#define VMCNT(N) VMCNT_(N)

#define SGB_DS(n) __builtin_amdgcn_sched_group_barrier(0x100, (n), 0)
#define SGB_MFMA(n) __builtin_amdgcn_sched_group_barrier(0x8, (n), 0)

// ---------------- rounding helpers (bit-exact vs numpy RTNE) -----------------

__device__ __forceinline__ float round_e4m3(float v) {
  if (v < 0.015625f) {                        // subnormal grid, step 2^-9
    return rintf(v * 512.0f) * 0.001953125f;
  }
  unsigned b = __float_as_uint(v);
  unsigned e = (b >> 23) & 0xFFu;
  float step = __uint_as_float((e - 3u) << 23); // 2^(e-127-3)
  return rintf(v / step) * step;
}

__device__ __forceinline__ float round_e2m1(float v) {
  float a = fabsf(v);
  float step = (a < 2.0f) ? 0.5f : ((a < 4.0f) ? 1.0f : 2.0f);
  float q = fminf(rintf(a / step) * step, 6.0f);
  return copysignf(q, v);
}

// ---------------- kernel 1: global amax of |x| and |w| ----------------------

__global__ void nvfp4_amax_kernel(const float* __restrict__ x,
                                  const float* __restrict__ w,
                                  unsigned* __restrict__ sc, int nx4, int nw4) {
  const float4* src = blockIdx.y ? (const float4*)w : (const float4*)x;
  int n4 = blockIdx.y ? nw4 : nx4;
  float m = 0.f;
  for (int i = blockIdx.x * blockDim.x + threadIdx.x; i < n4;
       i += gridDim.x * blockDim.x) {
    float4 v = src[i];
    m = fmaxf(m, fmaxf(fmaxf(fabsf(v.x), fabsf(v.y)),
                       fmaxf(fabsf(v.z), fabsf(v.w))));
  }
#pragma unroll
  for (int off = 32; off; off >>= 1) m = fmaxf(m, __shfl_down(m, off));
  __shared__ float red[4];
  if ((threadIdx.x & 63) == 0) red[threadIdx.x >> 6] = m;
  __syncthreads();
  if (threadIdx.x == 0) {
    m = fmaxf(fmaxf(red[0], red[1]), fmaxf(red[2], red[3]));
    atomicMax(&sc[blockIdx.y], __float_as_uint(m));
  }
}

// ------------- kernel 2/3: quantize->dequantize to bf16 ---------------------

__global__ void nvfp4_quant_kernel(const float* __restrict__ src,
                                   u16* __restrict__ dst,
                                   const unsigned* __restrict__ sc, int which,
                                   int nblk) {
  int idx = blockIdx.x * blockDim.x + threadIdx.x;
  if (idx >= nblk) return;
  float amax = fmaxf(__uint_as_float(sc[which]), 1e-12f);
  float gs = 2688.0f / amax;

  float4 v[4];
  const float4* p = (const float4*)src + (size_t)idx * 4;
  v[0] = p[0]; v[1] = p[1]; v[2] = p[2]; v[3] = p[3];
  const float* fv = (const float*)v;

  float bamax = 0.f;
#pragma unroll
  for (int i = 0; i < 16; ++i) bamax = fmaxf(bamax, fabsf(fv[i]));

  float sf = round_e4m3((bamax * gs) / 6.0f);
  float sfs = fmaxf(sf, 1e-12f);
  float r = gs / sfs;

  u16 ob[16];
#pragma unroll
  for (int i = 0; i < 16; ++i) {
    float q = round_e2m1(fv[i] * r);
    float d = q * sf;                        // exact in bf16
    ob[i] = (u16)(__float_as_uint(d) >> 16);
  }
  u16x8* o = (u16x8*)(dst + (size_t)idx * 16);
  o[0] = *(u16x8*)ob;
  o[1] = *(u16x8*)(ob + 8);
}

// ---------------- kernel 4: 256x256 bf16 GEMM ------------------------------
// 512 threads = 8 waves (2M x 4N), per-wave 128x64 = acc[8][4]. BK=32,
// ring-4 LDS. Per tile t (steady state, one segment):
//   STAGE_A(t+3); vmcnt(10); SBAR;
//   {bv0-3, av0 reads} MFMA row0 {av1} row1 {av2} row2 {av3} row3
//   STAGE_B(t+3)
//   {aw0} row4 {aw1} row5 {aw2} row6 {aw3} row7
//   SBAR;
// Each row's ds_read serve (~12cyc) hides under the previous row's 4 MFMA
// (~78cyc). sched_group_barrier pins the DS/MFMA interleave.
// vmcnt(10): 5 newer stage-units (2 loads each) allowed in flight ->
// forces tile t fully resident. WAR: stage for buf (t+3)&3=(t-1)&3 issues
// only after the barrier closing tile t-1's reads.

#define BM 256
#define BN 256
#define BK 32
#define TILE_E 8192   /* 256*32 u16 elements per ring buffer */

__global__ __launch_bounds__(512, 2) void nvfp4_gemm_kernel(
    const u16* __restrict__ A,   // dx [M][K]
    const u16* __restrict__ B,   // dw [N][K]
    const float* __restrict__ bias, const unsigned* __restrict__ sc,
    float* __restrict__ C, int M, int N, int K) {
  __shared__ u16 lA[4][TILE_E];
  __shared__ u16 lB[4][TILE_E];
  const u16* lAflat = &lA[0][0];
  const u16* lBflat = &lB[0][0];

  const int tid = threadIdx.x;
  const int lane = tid & 63;
  const int wv = tid >> 6;
  const int wm = wv >> 2;        // 0..1
  const int wn = wv & 3;         // 0..3

  // T1: XCD-aware swizzle (256 blocks, 8 XCDs x 32; 4x8 tile region per XCD)
  const int bid = blockIdx.x;
  const int xcd = bid & 7, loc = bid >> 3;
  const int tm0 = ((xcd & 3) * 4 + (loc & 3)) * BM;
  const int tn0 = ((xcd >> 2) * 8 + (loc >> 2)) * BN;

  // ---- staging addressing (pre-swizzled global source, linear LDS dest) ----
  const int srow = tid >> 2;                 // 0..127
  const int skey = (srow >> 1) & 3;
  const int scol = ((tid & 3) ^ skey) * 8;   // swizzled 8-elem slot
  const u16* gA0 = A + (size_t)(tm0 + srow) * K + scol;
  const u16* gA1 = A + (size_t)(tm0 + 128 + srow) * K + scol;
  const u16* gB0 = B + (size_t)(tn0 + srow) * K + scol;
  const u16* gB1 = B + (size_t)(tn0 + 128 + srow) * K + scol;
  const int ld0 = tid * 8;
  const int ld1 = tid * 8 + 4096;

#define STAGE_A(tt)                                                             \
  do {                                                                          \
    int _o = ((tt) & 3) * TILE_E;                                               \
    GLD_LDS(gA0 + (size_t)(tt) * BK, lAflat + _o + ld0);                        \
    GLD_LDS(gA1 + (size_t)(tt) * BK, lAflat + _o + ld1);                        \
  } while (0)
#define STAGE_B(tt)                                                             \
  do {                                                                          \
    int _o = ((tt) & 3) * TILE_E;                                               \
    GLD_LDS(gB0 + (size_t)(tt) * BK, lBflat + _o + ld0);                        \
    GLD_LDS(gB1 + (size_t)(tt) * BK, lBflat + _o + ld1);                        \
  } while (0)

  // ---- fragment addressing (T2 swizzle on read side, same involution) ------
  const int rb = lane & 15;
  const int cc = (((lane >> 4) ^ ((rb >> 1) & 3)) << 3);
  const int aoff = (wm * 128 + rb) * BK + cc;  // row i: +i*512; ih1: +2048
  const int boff = (wn * 64 + rb) * BK + cc;

#define MFMA_ROW(r, AV)                                                         \
  do {                                                                          \
    acc[r][0] = __builtin_amdgcn_mfma_f32_16x16x32_bf16(AV, bv0, acc[r][0], 0, 0, 0); \
    acc[r][1] = __builtin_amdgcn_mfma_f32_16x16x32_bf16(AV, bv1, acc[r][1], 0, 0, 0); \
    acc[r][2] = __builtin_amdgcn_mfma_f32_16x16x32_bf16(AV, bv2, acc[r][2], 0, 0, 0); \
    acc[r][3] = __builtin_amdgcn_mfma_f32_16x16x32_bf16(AV, bv3, acc[r][3], 0, 0, 0); \
  } while (0)

#define TILE_BODY(t, VM, STA, STB)                                              \
  do {                                                                          \
    if (STA) STAGE_A((t) + 3);                                                  \
    VMCNT(VM);                                                                  \
    SBAR();                                                                     \
    const u16* _ba = lAflat + ((t) & 3) * TILE_E;                               \
    const u16* _bb = lBflat + ((t) & 3) * TILE_E;                               \
    bf16x8 bv0 = *(const bf16x8*)(_bb + boff);                                  \
    bf16x8 bv1 = *(const bf16x8*)(_bb + boff + 512);                            \
    bf16x8 bv2 = *(const bf16x8*)(_bb + boff + 1024);                           \
    bf16x8 bv3 = *(const bf16x8*)(_bb + boff + 1536);                           \
    bf16x8 a0 = *(const bf16x8*)(_ba + aoff);                                   \
    SGB_DS(5);                                                                  \
    __builtin_amdgcn_s_setprio(1);                                              \
    MFMA_ROW(0, a0);                                                            \
    SGB_MFMA(4);                                                                \
    bf16x8 a1 = *(const bf16x8*)(_ba + aoff + 512);                             \
    SGB_DS(1);                                                                  \
    MFMA_ROW(1, a1);                                                            \
    SGB_MFMA(4);                                                                \
    bf16x8 a2 = *(const bf16x8*)(_ba + aoff + 1024);                            \
    SGB_DS(1);                                                                  \
    MFMA_ROW(2, a2);                                                            \
    SGB_MFMA(4);                                                                \
    bf16x8 a3 = *(const bf16x8*)(_ba + aoff + 1536);                            \
    SGB_DS(1);                                                                  \
    MFMA_ROW(3, a3);                                                            \
    SGB_MFMA(4);                                                                \
    __builtin_amdgcn_s_setprio(0);                                              \
    if (STB) STAGE_B((t) + 3);                                                  \
    __builtin_amdgcn_s_setprio(1);                                              \
    bf16x8 a4 = *(const bf16x8*)(_ba + aoff + 2048);                            \
    SGB_DS(1);                                                                  \
    MFMA_ROW(4, a4);                                                            \
    SGB_MFMA(4);                                                                \
    bf16x8 a5 = *(const bf16x8*)(_ba + aoff + 2560);                            \
    SGB_DS(1);                                                                  \
    MFMA_ROW(5, a5);                                                            \
    SGB_MFMA(4);                                                                \
    bf16x8 a6 = *(const bf16x8*)(_ba + aoff + 3072);                            \
    SGB_DS(1);                                                                  \
    MFMA_ROW(6, a6);                                                            \
    SGB_MFMA(4);                                                                \
    bf16x8 a7 = *(const bf16x8*)(_ba + aoff + 3584);                            \
    SGB_DS(1);                                                                  \
    MFMA_ROW(7, a7);                                                            \
    SGB_MFMA(4);                                                                \
    __builtin_amdgcn_s_setprio(0);                                              \
    SBAR();                                                                     \
  } while (0)

  f32x4 acc[8][4] = {};

  // prologue: stage tiles 0,1,2 fully (6 units = 12 loads)
  STAGE_A(0); STAGE_B(0);
  STAGE_A(1); STAGE_B(1);
  STAGE_A(2); STAGE_B(2);

  // main: tiles 0..124 (stage t+3), tail 125..127
  for (int t = 0; t < 125; ++t) {
    TILE_BODY(t, 10, 1, 1);
  }
  TILE_BODY(125, 8, 0, 0);
  TILE_BODY(126, 4, 0, 0);
  TILE_BODY(127, 0, 0, 0);

  // ---------------- epilogue: out = alpha*acc + bias ------------------------
  float ax = fmaxf(__uint_as_float(sc[0]), 1e-12f);
  float aw_ = fmaxf(__uint_as_float(sc[1]), 1e-12f);
  float alpha = (ax * aw_) / 7225344.0f;     // amax_x*amax_w / 2688^2

  const int orow = (lane >> 4) * 4;          // C/D: col=lane&15, row=(lane>>4)*4+reg
  const int ocol = lane & 15;
#pragma unroll
  for (int ai = 0; ai < 8; ++ai) {
#pragma unroll
    for (int j = 0; j < 4; ++j) {
      int col = tn0 + wn * 64 + j * 16 + ocol;
      float bvv = bias[col];
#pragma unroll
      for (int rr = 0; rr < 4; ++rr) {
        int row = tm0 + wm * 128 + ai * 16 + orow + rr;
        C[(size_t)row * N + col] = alpha * acc[ai][j][rr] + bvv;
      }
    }
  }
#undef STAGE_A
#undef STAGE_B
#undef MFMA_ROW
#undef TILE_BODY
}

// ---------------------------------------------------------------------------

extern "C" void kernel_launch(void* const* d_in, const int* in_sizes, int n_in,
                              void* d_out, int out_size, void* d_ws, size_t ws_size,
                              hipStream_t stream) {
  const float* x = (const float*)d_in[0];
  const float* w = (const float*)d_in[1];
  const float* bias = (const float*)d_in[2];
  float* out = (float*)d_out;

  const int N = in_sizes[2];
  const int K = in_sizes[1] / N;
  const int M = in_sizes[0] / K;

  unsigned char* ws = (unsigned char*)d_ws;
  unsigned* sc = (unsigned*)ws;
  u16* dx = (u16*)(ws + 256);
  u16* dw = (u16*)(ws + 256 + (size_t)M * K * sizeof(u16));

  hipMemsetAsync(sc, 0, 8, stream);

  nvfp4_amax_kernel<<<dim3(1024, 2), 256, 0, stream>>>(x, w, sc, M * K / 4,
                                                       N * K / 4);

  int nbx = M * K / 16, nbw = N * K / 16;
  nvfp4_quant_kernel<<<(nbx + 255) / 256, 256, 0, stream>>>(x, dx, sc, 0, nbx);
  nvfp4_quant_kernel<<<(nbw + 255) / 256, 256, 0, stream>>>(w, dw, sc, 1, nbw);

  nvfp4_gemm_kernel<<<dim3((M / BM) * (N / BN)), 512, 0, stream>>>(
      dx, dw, bias, sc, out, M, N, K);
}

// Round 7
// 206.244 us; speedup vs baseline: 1.0635x; 1.0635x over previous
//
#include <hip/hip_runtime.h>
#include <hip/hip_bf16.h>

// NVFP4 dynamic linear: x[2,2048,4096] f32, w[4096,4096] f32, bias[4096] -> out f32
// M=4096, N=4096, K=4096.
//
// amax -> quant/dequant to bf16 (exact: e2m1 code x e4m3 scale fits bf16;
// products accumulate exactly in fp32 MFMA) -> 256x256 bf16 MFMA GEMM,
// m201-style 8-phase schedule (BK=64, 2 K-tiles per 8 phases), counted
// vmcnt, LDS XOR swizzle, XCD swizzle, setprio.
//
// ws: [0,8) amax bits | [256, +32MB) dx bf16 | [+32MB) dw bf16

typedef unsigned short u16;
typedef __bf16 bf16x8 __attribute__((ext_vector_type(8)));
typedef float f32x4 __attribute__((ext_vector_type(4)));
typedef unsigned short u16x8 __attribute__((ext_vector_type(8)));

#define GLD_LDS(gsrc, ldst)                                                     \
  __builtin_amdgcn_global_load_lds(                                             \
      (const __attribute__((address_space(1))) void*)(gsrc),                    \
      (__attribute__((address_space(3))) void*)(ldst), 16, 0, 0)

#define SBAR()                                                                  \
  do {                                                                          \
    asm volatile("" ::: "memory");                                              \
    __builtin_amdgcn_s_barrier();                                               \
    asm volatile("" ::: "memory");                                              \
  } while (0)

#define VMCNT_(N) asm volatile("s_waitcnt vmcnt(" #N ")" ::: "memory")
#define VMCNT(N) VMCNT_(N)

// ---------------- rounding helpers (bit-exact vs numpy RTNE) -----------------

__device__ __forceinline__ float round_e4m3(float v) {
  if (v < 0.015625f) {                        // subnormal grid, step 2^-9
    return rintf(v * 512.0f) * 0.001953125f;
  }
  unsigned b = __float_as_uint(v);
  unsigned e = (b >> 23) & 0xFFu;
  float step = __uint_as_float((e - 3u) << 23); // 2^(e-127-3)
  return rintf(v / step) * step;
}

__device__ __forceinline__ float round_e2m1(float v) {
  float a = fabsf(v);
  float step = (a < 2.0f) ? 0.5f : ((a < 4.0f) ? 1.0f : 2.0f);
  float q = fminf(rintf(a / step) * step, 6.0f);
  return copysignf(q, v);
}

// ---------------- kernel 1: global amax of |x| and |w| ----------------------

__global__ void nvfp4_amax_kernel(const float* __restrict__ x,
                                  const float* __restrict__ w,
                                  unsigned* __restrict__ sc, int nx4, int nw4) {
  const float4* src = blockIdx.y ? (const float4*)w : (const float4*)x;
  int n4 = blockIdx.y ? nw4 : nx4;
  float m = 0.f;
  for (int i = blockIdx.x * blockDim.x + threadIdx.x; i < n4;
       i += gridDim.x * blockDim.x) {
    float4 v = src[i];
    m = fmaxf(m, fmaxf(fmaxf(fabsf(v.x), fabsf(v.y)),
                       fmaxf(fabsf(v.z), fabsf(v.w))));
  }
#pragma unroll
  for (int off = 32; off; off >>= 1) m = fmaxf(m, __shfl_down(m, off));
  __shared__ float red[4];
  if ((threadIdx.x & 63) == 0) red[threadIdx.x >> 6] = m;
  __syncthreads();
  if (threadIdx.x == 0) {
    m = fmaxf(fmaxf(red[0], red[1]), fmaxf(red[2], red[3]));
    atomicMax(&sc[blockIdx.y], __float_as_uint(m));
  }
}

// ------------- kernel 2/3: quantize->dequantize to bf16 ---------------------

__global__ void nvfp4_quant_kernel(const float* __restrict__ src,
                                   u16* __restrict__ dst,
                                   const unsigned* __restrict__ sc, int which,
                                   int nblk) {
  int idx = blockIdx.x * blockDim.x + threadIdx.x;
  if (idx >= nblk) return;
  float amax = fmaxf(__uint_as_float(sc[which]), 1e-12f);
  float gs = 2688.0f / amax;

  float4 v[4];
  const float4* p = (const float4*)src + (size_t)idx * 4;
  v[0] = p[0]; v[1] = p[1]; v[2] = p[2]; v[3] = p[3];
  const float* fv = (const float*)v;

  float bamax = 0.f;
#pragma unroll
  for (int i = 0; i < 16; ++i) bamax = fmaxf(bamax, fabsf(fv[i]));

  float sf = round_e4m3((bamax * gs) / 6.0f);
  float sfs = fmaxf(sf, 1e-12f);
  float r = gs / sfs;

  u16 ob[16];
#pragma unroll
  for (int i = 0; i < 16; ++i) {
    float q = round_e2m1(fv[i] * r);
    float d = q * sf;                        // exact in bf16
    ob[i] = (u16)(__float_as_uint(d) >> 16);
  }
  u16x8* o = (u16x8*)(dst + (size_t)idx * 16);
  o[0] = *(u16x8*)ob;
  o[1] = *(u16x8*)(ob + 8);
}

// ---------------- kernel 4: 256x256 bf16 GEMM, m201-style 8-phase ----------
// 512 threads = 8 waves (2M x 4N). Per-wave C = 128x64 as 4 strips of 32x64:
// strip s = rows s*64 + wm*32 .. +31 (strips 0,1 in A-half0; 2,3 in A-half1).
// BK=64, LDS = [2 dbuf][2 half] per matrix (ring-4 half-slots, 128 KiB).
// Per K-tile t (4 phases):
//  ph1: read B(8: 4 cols x 2 ksteps, once per tile) + strip0 A(4);
//       stage Ah1(t+1); bar; 16 MFMA; bar
//  ph2: read strip1 A(4); stage Bh0(t+2); bar; 16 MFMA; vmcnt(10); bar
//  ph3: read strip2 A(4); stage Bh1(t+2); bar; 16 MFMA; bar
//  ph4: read strip3 A(4); stage Ah0(t+2); bar; 16 MFMA; vmcnt(8); bar
// vmcnt(10) guards Ah1(t) (staged t-1 ph1, 5 halves behind it);
// vmcnt(8) guards {Bh0,Bh1,Ah0}(t+1) (staged t-1 ph2-4, 4 halves behind).
// Issue->require slack >= 4 phases everywhere; never vmcnt(0) until tail.
// WAR: every half-slot has >=2 barriers between last ds_read and next stage.

#define BM 256
#define BN 256
#define BK 64
#define HALF_E (128 * 64)   /* elems per half-tile buffer */

__global__ __launch_bounds__(512, 2) void nvfp4_gemm_kernel(
    const u16* __restrict__ A,   // dx [M][K]
    const u16* __restrict__ B,   // dw [N][K]
    const float* __restrict__ bias, const unsigned* __restrict__ sc,
    float* __restrict__ C, int M, int N, int K) {
  __shared__ u16 lA[2][2][HALF_E];
  __shared__ u16 lB[2][2][HALF_E];

  const int tid = threadIdx.x;
  const int lane = tid & 63;
  const int wv = tid >> 6;
  const int wm = wv >> 2;        // 0..1
  const int wn = wv & 3;         // 0..3

  // T1: XCD-aware swizzle (256 blocks, 8 XCDs x 32; 4x8 tile region per XCD)
  const int bid = blockIdx.x;
  const int xcd = bid & 7, loc = bid >> 3;
  const int tm0 = ((xcd & 3) * 4 + (loc & 3)) * BM;
  const int tn0 = ((xcd >> 2) * 8 + (loc >> 2)) * BN;

  // ---- staging addressing (pre-swizzled global source, linear LDS dest) ----
  // One gload_lds inst/wave covers 1KB = 8 rows x 128B. lane l -> row +l>>3,
  // slot l&7. Global col = (slot ^ (row&7))*8 = ((l&7)^(l>>3))*8.
  const int sr = lane >> 3;                      // 0..7
  const int sc8 = ((lane & 7) ^ sr) * 8;         // pre-swizzled col (elems)
  const int srow0 = wv * 16 + sr;                // rows: +i*8, +h*128
  const u16* gA = A + (size_t)(tm0 + srow0) * K + sc8;
  const u16* gB = B + (size_t)(tn0 + srow0) * K + sc8;
  const int ldst = wv * 1024 + lane * 8;         // + i*512 (elems)

#define STAGE_AH0(tt)                                                           \
  do {                                                                          \
    u16* _d = &lA[(tt) & 1][0][0] + ldst;                                       \
    const u16* _g = gA + (size_t)(tt) * BK;                                     \
    GLD_LDS(_g, _d); GLD_LDS(_g + 8 * (size_t)K, _d + 512);                     \
  } while (0)
#define STAGE_AH1(tt)                                                           \
  do {                                                                          \
    u16* _d = &lA[(tt) & 1][1][0] + ldst;                                       \
    const u16* _g = gA + 128 * (size_t)K + (size_t)(tt) * BK;                   \
    GLD_LDS(_g, _d); GLD_LDS(_g + 8 * (size_t)K, _d + 512);                     \
  } while (0)
#define STAGE_BH0(tt)                                                           \
  do {                                                                          \
    u16* _d = &lB[(tt) & 1][0][0] + ldst;                                       \
    const u16* _g = gB + (size_t)(tt) * BK;                                     \
    GLD_LDS(_g, _d); GLD_LDS(_g + 8 * (size_t)K, _d + 512);                     \
  } while (0)
#define STAGE_BH1(tt)                                                           \
  do {                                                                          \
    u16* _d = &lB[(tt) & 1][1][0] + ldst;                                       \
    const u16* _g = gB + 128 * (size_t)K + (size_t)(tt) * BK;                   \
    GLD_LDS(_g, _d); GLD_LDS(_g + 8 * (size_t)K, _d + 512);                     \
  } while (0)

  // ---- fragment read addressing (T2 swizzle, same involution as stage) -----
  const int rb = lane & 15;
  const int k7 = lane & 7;                       // == row&7 for all frag rows
  const int sl = lane >> 4;                      // 0..3
  const int cck0 = (sl ^ k7) * 8;                // kstep 0 swizzled slot
  const int cck1 = ((4 + sl) ^ k7) * 8;          // kstep 1
  const int arow_off = (wm * 32 + rb) * BK;      // + (s&1)*4096 + r*1024
  const int brow_off = ((wn & 1) * 64 + rb) * BK; // + c*1024

#define READ_A(s, bA)                                                           \
  do {                                                                          \
    const u16* _p = (bA) + ((s) >> 1) * HALF_E + ((s) & 1) * 4096 + arow_off;   \
    a00 = *(const bf16x8*)(_p + cck0);                                          \
    a01 = *(const bf16x8*)(_p + cck1);                                          \
    a10 = *(const bf16x8*)(_p + 1024 + cck0);                                   \
    a11 = *(const bf16x8*)(_p + 1024 + cck1);                                   \
  } while (0)

#define MFMA_S(s)                                                               \
  do {                                                                          \
    _Pragma("unroll") for (int _c = 0; _c < 4; ++_c) {                          \
      acc[s][0][_c] = __builtin_amdgcn_mfma_f32_16x16x32_bf16(                  \
          a00, bv[_c][0], acc[s][0][_c], 0, 0, 0);                              \
      acc[s][0][_c] = __builtin_amdgcn_mfma_f32_16x16x32_bf16(                  \
          a01, bv[_c][1], acc[s][0][_c], 0, 0, 0);                              \
      acc[s][1][_c] = __builtin_amdgcn_mfma_f32_16x16x32_bf16(                  \
          a10, bv[_c][0], acc[s][1][_c], 0, 0, 0);                              \
      acc[s][1][_c] = __builtin_amdgcn_mfma_f32_16x16x32_bf16(                  \
          a11, bv[_c][1], acc[s][1][_c], 0, 0, 0);                              \
    }                                                                           \
  } while (0)

#define SETP1() __builtin_amdgcn_s_setprio(1)
#define SETP0() __builtin_amdgcn_s_setprio(0)

#define TILE(t, SA1, S2, VMID, VEND)                                            \
  do {                                                                          \
    const u16* _bA = &lA[(t) & 1][0][0];                                        \
    const u16* _bB = &lB[(t) & 1][0][0] + (wn >> 1) * HALF_E + brow_off;        \
    bf16x8 bv[4][2], a00, a01, a10, a11;                                        \
    _Pragma("unroll") for (int _c = 0; _c < 4; ++_c) {                          \
      bv[_c][0] = *(const bf16x8*)(_bB + _c * 1024 + cck0);                     \
      bv[_c][1] = *(const bf16x8*)(_bB + _c * 1024 + cck1);                     \
    }                                                                           \
    READ_A(0, _bA);                                                             \
    if (SA1) STAGE_AH1((t) + 1);                                                \
    SBAR();                                                                     \
    SETP1(); MFMA_S(0); SETP0();                                                \
    SBAR();                                                                     \
    READ_A(1, _bA);                                                             \
    if (S2) STAGE_BH0((t) + 2);                                                 \
    SBAR();                                                                     \
    SETP1(); MFMA_S(1); SETP0();                                                \
    VMCNT(VMID);                                                                \
    SBAR();                                                                     \
    READ_A(2, _bA);                                                             \
    if (S2) STAGE_BH1((t) + 2);                                                 \
    SBAR();                                                                     \
    SETP1(); MFMA_S(2); SETP0();                                                \
    SBAR();                                                                     \
    READ_A(3, _bA);                                                             \
    if (S2) STAGE_AH0((t) + 2);                                                 \
    SBAR();                                                                     \
    SETP1(); MFMA_S(3); SETP0();                                                \
    VMCNT(VEND);                                                                \
    SBAR();                                                                     \
  } while (0)

  f32x4 acc[4][2][4] = {};
  const int NT = K / BK;                         // 64

  // prologue: stage Bh0(0),Bh1(0),Ah0(0),Ah1(0),Bh0(1),Bh1(1),Ah0(1)
  STAGE_BH0(0); STAGE_BH1(0); STAGE_AH0(0); STAGE_AH1(0);
  STAGE_BH0(1); STAGE_BH1(1); STAGE_AH0(1);
  VMCNT(8);                                      // first 3 halves resident
  SBAR();

  for (int t = 0; t < NT - 2; ++t) {
    TILE(t, 1, 1, 10, 8);
  }
  TILE(NT - 2, 1, 0, 8, 2);
  TILE(NT - 1, 0, 0, 0, 0);

  // ---------------- epilogue: out = alpha*acc + bias ------------------------
  float ax = fmaxf(__uint_as_float(sc[0]), 1e-12f);
  float aww = fmaxf(__uint_as_float(sc[1]), 1e-12f);
  float alpha = (ax * aww) / 7225344.0f;         // amax_x*amax_w / 2688^2

  const int orow = (lane >> 4) * 4;              // C/D: col=lane&15, row=(lane>>4)*4+reg
  const int ocol = lane & 15;
#pragma unroll
  for (int s = 0; s < 4; ++s) {
#pragma unroll
    for (int r = 0; r < 2; ++r) {
#pragma unroll
      for (int c = 0; c < 4; ++c) {
        int col = tn0 + wn * 64 + c * 16 + ocol;
        float bvv = bias[col];
#pragma unroll
        for (int rr = 0; rr < 4; ++rr) {
          int row = tm0 + s * 64 + wm * 32 + r * 16 + orow + rr;
          C[(size_t)row * N + col] = alpha * acc[s][r][c][rr] + bvv;
        }
      }
    }
  }
#undef STAGE_AH0
#undef STAGE_AH1
#undef STAGE_BH0
#undef STAGE_BH1
#undef READ_A
#undef MFMA_S
#undef TILE
}

// ---------------------------------------------------------------------------

extern "C" void kernel_launch(void* const* d_in, const int* in_sizes, int n_in,
                              void* d_out, int out_size, void* d_ws, size_t ws_size,
                              hipStream_t stream) {
  const float* x = (const float*)d_in[0];
  const float* w = (const float*)d_in[1];
  const float* bias = (const float*)d_in[2];
  float* out = (float*)d_out;

  const int N = in_sizes[2];
  const int K = in_sizes[1] / N;
  const int M = in_sizes[0] / K;

  unsigned char* ws = (unsigned char*)d_ws;
  unsigned* sc = (unsigned*)ws;
  u16* dx = (u16*)(ws + 256);
  u16* dw = (u16*)(ws + 256 + (size_t)M * K * sizeof(u16));

  hipMemsetAsync(sc, 0, 8, stream);

  nvfp4_amax_kernel<<<dim3(1024, 2), 256, 0, stream>>>(x, w, sc, M * K / 4,
                                                       N * K / 4);

  int nbx = M * K / 16, nbw = N * K / 16;
  nvfp4_quant_kernel<<<(nbx + 255) / 256, 256, 0, stream>>>(x, dx, sc, 0, nbx);
  nvfp4_quant_kernel<<<(nbw + 255) / 256, 256, 0, stream>>>(w, dw, sc, 1, nbw);

  nvfp4_gemm_kernel<<<dim3((M / BM) * (N / BN)), 512, 0, stream>>>(
      dx, dw, bias, sc, out, M, N, K);
}

// Round 8
// 198.450 us; speedup vs baseline: 1.1053x; 1.0393x over previous
//
#include <hip/hip_runtime.h>
#include <hip/hip_bf16.h>

// NVFP4 dynamic linear: x[2,2048,4096] f32, w[4096,4096] f32, bias[4096] -> out f32
// M=4096, N=4096, K=4096.
//
// amax -> quant/dequant to bf16 (exact: e2m1 code x e4m3 scale fits bf16;
// products accumulate exactly in fp32 MFMA) -> 256x256 bf16 MFMA GEMM.
// GEMM = round-3 structure (ring-4 LDS, BK=32, 2-tile groups, counted vmcnt)
// + fragment-register WAR fix: ds_reads of phase p+1 write registers whose
// consuming MFMAs issued at phase p-1 (>=2-phase gap), so the LDS serve
// overlaps the matrix-pipe drain instead of stalling on the WAR interlock.
//
// ws: [0,8) amax bits | [256, +32MB) dx bf16 | [+32MB) dw bf16

typedef unsigned short u16;
typedef __bf16 bf16x8 __attribute__((ext_vector_type(8)));
typedef float f32x4 __attribute__((ext_vector_type(4)));
typedef unsigned short u16x8 __attribute__((ext_vector_type(8)));

#define GLD_LDS(gsrc, ldst)                                                     \
  __builtin_amdgcn_global_load_lds(                                             \
      (const __attribute__((address_space(1))) void*)(gsrc),                    \
      (__attribute__((address_space(3))) void*)(ldst), 16, 0, 0)

#define SBAR()                                                                  \
  do {                                                                          \
    asm volatile("" ::: "memory");                                              \
    __builtin_amdgcn_s_barrier();                                               \
    asm volatile("" ::: "memory");                                              \
  } while (0)

#define VMCNT_(N) asm volatile("s_waitcnt vmcnt(" #N ")" ::: "memory")
#define VMCNT(N) VMCNT_(N)

// keep a fragment set live (0 instructions) so the register allocator cannot
// recycle its registers for a later set -> preserves the >=2-phase WAR gap.
#define KEEP4(S) asm volatile("" ::"v"(S[0]), "v"(S[1]), "v"(S[2]), "v"(S[3]))

// ---------------- rounding helpers (bit-exact vs numpy RTNE) -----------------

__device__ __forceinline__ float round_e4m3(float v) {
  if (v < 0.015625f) {                        // subnormal grid, step 2^-9
    return rintf(v * 512.0f) * 0.001953125f;
  }
  unsigned b = __float_as_uint(v);
  unsigned e = (b >> 23) & 0xFFu;
  float step = __uint_as_float((e - 3u) << 23); // 2^(e-127-3)
  return rintf(v / step) * step;
}

__device__ __forceinline__ float round_e2m1(float v) {
  float a = fabsf(v);
  float step = (a < 2.0f) ? 0.5f : ((a < 4.0f) ? 1.0f : 2.0f);
  float q = fminf(rintf(a / step) * step, 6.0f);
  return copysignf(q, v);
}

// ---------------- kernel 1: global amax of |x| and |w| ----------------------

__global__ void nvfp4_amax_kernel(const float* __restrict__ x,
                                  const float* __restrict__ w,
                                  unsigned* __restrict__ sc, int nx4, int nw4) {
  const float4* src = blockIdx.y ? (const float4*)w : (const float4*)x;
  int n4 = blockIdx.y ? nw4 : nx4;
  float m = 0.f;
  for (int i = blockIdx.x * blockDim.x + threadIdx.x; i < n4;
       i += gridDim.x * blockDim.x) {
    float4 v = src[i];
    m = fmaxf(m, fmaxf(fmaxf(fabsf(v.x), fabsf(v.y)),
                       fmaxf(fabsf(v.z), fabsf(v.w))));
  }
#pragma unroll
  for (int off = 32; off; off >>= 1) m = fmaxf(m, __shfl_down(m, off));
  __shared__ float red[4];
  if ((threadIdx.x & 63) == 0) red[threadIdx.x >> 6] = m;
  __syncthreads();
  if (threadIdx.x == 0) {
    m = fmaxf(fmaxf(red[0], red[1]), fmaxf(red[2], red[3]));
    atomicMax(&sc[blockIdx.y], __float_as_uint(m));
  }
}

// ------------- kernel 2/3: quantize->dequantize to bf16 ---------------------

__global__ void nvfp4_quant_kernel(const float* __restrict__ src,
                                   u16* __restrict__ dst,
                                   const unsigned* __restrict__ sc, int which,
                                   int nblk) {
  int idx = blockIdx.x * blockDim.x + threadIdx.x;
  if (idx >= nblk) return;
  float amax = fmaxf(__uint_as_float(sc[which]), 1e-12f);
  float gs = 2688.0f / amax;

  float4 v[4];
  const float4* p = (const float4*)src + (size_t)idx * 4;
  v[0] = p[0]; v[1] = p[1]; v[2] = p[2]; v[3] = p[3];
  const float* fv = (const float*)v;

  float bamax = 0.f;
#pragma unroll
  for (int i = 0; i < 16; ++i) bamax = fmaxf(bamax, fabsf(fv[i]));

  float sf = round_e4m3((bamax * gs) / 6.0f);
  float sfs = fmaxf(sf, 1e-12f);
  float r = gs / sfs;

  u16 ob[16];
#pragma unroll
  for (int i = 0; i < 16; ++i) {
    float q = round_e2m1(fv[i] * r);
    float d = q * sf;                        // exact in bf16
    ob[i] = (u16)(__float_as_uint(d) >> 16);
  }
  u16x8* o = (u16x8*)(dst + (size_t)idx * 16);
  o[0] = *(u16x8*)ob;
  o[1] = *(u16x8*)(ob + 8);
}

// ---------------- kernel 4: 256x256 bf16 GEMM, ring-4 + WAR-safe frags -----
// 512 threads = 8 waves (2M x 4N), per-wave 128x64 = acc[8][4]. BK=32.
// Group = 2 K-tiles (t0,t1) = 4 phases. Fragment register sets:
//   av: written P0 (t0 rows 0-63) and P2 (t1) -> rewrite gap 2 phases
//   aw: written P1 (t0 rows 64-127) and P3 (t1) -> gap 2
//   bve: written P0 (t0 B), consumed P0+P1, rewritten next-group P0 -> gap 3
//   bvo: written P2 (t1 B), consumed P2+P3, rewritten next-group P2 -> gap 3
// => every ds_read targets registers whose consuming MFMAs issued >=2 phases
// earlier (pipe drained) -> no WAR interlock; serve overlaps MFMA drain.
// Staging/vmcnt identical to round 3: stage A(s0) P0, B(s0) P1, A(s1) P2,
// B(s1) P3; vmcnt(8) at P1-end and P3-end (4-phase issue->require slack).

#define BM 256
#define BN 256
#define BK 32

__global__ __launch_bounds__(512, 2) void nvfp4_gemm_kernel(
    const u16* __restrict__ A,   // dx [M][K]
    const u16* __restrict__ B,   // dw [N][K]
    const float* __restrict__ bias, const unsigned* __restrict__ sc,
    float* __restrict__ C, int M, int N, int K) {
  __shared__ u16 lA[4][BM * BK];
  __shared__ u16 lB[4][BN * BK];

  const int tid = threadIdx.x;
  const int lane = tid & 63;
  const int wv = tid >> 6;
  const int wm = wv >> 2;        // 0..1
  const int wn = wv & 3;         // 0..3

  // T1: XCD-aware swizzle (256 blocks, 8 XCDs x 32; 4x8 tile region per XCD)
  const int bid = blockIdx.x;
  const int xcd = bid & 7, loc = bid >> 3;
  const int tm0 = ((xcd & 3) * 4 + (loc & 3)) * BM;
  const int tn0 = ((xcd >> 2) * 8 + (loc >> 2)) * BN;

  // ---- staging addressing (pre-swizzled global source, linear LDS dest) ----
  const int srow = tid >> 2;                 // 0..127
  const int skey = (srow >> 1) & 3;
  const int scol = ((tid & 3) ^ skey) * 8;   // swizzled 8-elem slot
  const u16* gA0 = A + (size_t)(tm0 + srow) * K + scol;
  const u16* gA1 = A + (size_t)(tm0 + 128 + srow) * K + scol;
  const u16* gB0 = B + (size_t)(tn0 + srow) * K + scol;
  const u16* gB1 = B + (size_t)(tn0 + 128 + srow) * K + scol;
  const int ld0 = tid * 8;
  const int ld1 = tid * 8 + 4096;

#define STAGE_A(tt)                                                             \
  do {                                                                          \
    int _b = (tt) & 3;                                                          \
    GLD_LDS(gA0 + (size_t)(tt) * BK, &lA[_b][ld0]);                             \
    GLD_LDS(gA1 + (size_t)(tt) * BK, &lA[_b][ld1]);                             \
  } while (0)
#define STAGE_B(tt)                                                             \
  do {                                                                          \
    int _b = (tt) & 3;                                                          \
    GLD_LDS(gB0 + (size_t)(tt) * BK, &lB[_b][ld0]);                             \
    GLD_LDS(gB1 + (size_t)(tt) * BK, &lB[_b][ld1]);                             \
  } while (0)

  // ---- fragment addressing (T2 swizzle on read side, same involution) ------
  const int rb = lane & 15;
  const int cc = (((lane >> 4) ^ ((rb >> 1) & 3)) << 3);
  const int arow = wm * 128 + rb;            // + ih*64 + i*16
  const int brow = wn * 64 + rb;             // + j*16

  f32x4 acc[8][4] = {};
  const int NT = K / BK;                     // 128
  const int NG = NT / 2;                     // 64 groups of 2 tiles

  // prologue: stage tiles 0,1,2 (12 loads); vmcnt(8) -> tile 0 resident
  STAGE_A(0); STAGE_B(0);
  STAGE_A(1); STAGE_B(1);
  STAGE_A(2); STAGE_B(2);
  asm volatile("s_waitcnt vmcnt(8)" ::: "memory");
  SBAR();

  bf16x8 av[4], aw[4], bve[4], bvo[4];

  for (int g = 0; g < NG; ++g) {
    const int t0 = 2 * g, t1 = 2 * g + 1;
    const int s0 = 2 * g + 3, s1 = 2 * g + 4;  // tiles staged this group
    const u16* bufA0 = lA[t0 & 3];
    const u16* bufB0 = lB[t0 & 3];
    const u16* bufA1 = lA[t1 & 3];
    const u16* bufB1 = lB[t1 & 3];

    // ---------------- P0: tile t0, rows 0-63 (av x bve) -------------------
#pragma unroll
    for (int j = 0; j < 4; ++j)
      bve[j] = *(const bf16x8*)(bufB0 + (brow + j * 16) * BK + cc);
#pragma unroll
    for (int i = 0; i < 4; ++i)
      av[i] = *(const bf16x8*)(bufA0 + (arow + i * 16) * BK + cc);
    if (s0 < NT) STAGE_A(s0);
    SBAR();
    __builtin_amdgcn_s_setprio(1);
#pragma unroll
    for (int i = 0; i < 4; ++i)
#pragma unroll
      for (int j = 0; j < 4; ++j)
        acc[i][j] = __builtin_amdgcn_mfma_f32_16x16x32_bf16(av[i], bve[j],
                                                            acc[i][j], 0, 0, 0);
    __builtin_amdgcn_s_setprio(0);
    SBAR();

    // ---------------- P1: tile t0, rows 64-127 (aw x bve) -----------------
#pragma unroll
    for (int i = 0; i < 4; ++i)
      aw[i] = *(const bf16x8*)(bufA0 + (arow + 64 + i * 16) * BK + cc);
    if (s0 < NT) STAGE_B(s0);
    SBAR();
    __builtin_amdgcn_s_setprio(1);
#pragma unroll
    for (int i = 0; i < 4; ++i)
#pragma unroll
      for (int j = 0; j < 4; ++j)
        acc[4 + i][j] = __builtin_amdgcn_mfma_f32_16x16x32_bf16(aw[i], bve[j],
                                                                acc[4 + i][j],
                                                                0, 0, 0);
    __builtin_amdgcn_s_setprio(0);
    KEEP4(av);                               // av-P0 regs stay distinct from aw
    if (g < NG - 1) asm volatile("s_waitcnt vmcnt(8)" ::: "memory");
    else            asm volatile("s_waitcnt vmcnt(0)" ::: "memory");
    SBAR();

    // ---------------- P2: tile t1, rows 0-63 (av x bvo) -------------------
#pragma unroll
    for (int j = 0; j < 4; ++j)
      bvo[j] = *(const bf16x8*)(bufB1 + (brow + j * 16) * BK + cc);
#pragma unroll
    for (int i = 0; i < 4; ++i)
      av[i] = *(const bf16x8*)(bufA1 + (arow + i * 16) * BK + cc);
    if (s1 < NT) STAGE_A(s1);
    SBAR();
    __builtin_amdgcn_s_setprio(1);
#pragma unroll
    for (int i = 0; i < 4; ++i)
#pragma unroll
      for (int j = 0; j < 4; ++j)
        acc[i][j] = __builtin_amdgcn_mfma_f32_16x16x32_bf16(av[i], bvo[j],
                                                            acc[i][j], 0, 0, 0);
    __builtin_amdgcn_s_setprio(0);
    SBAR();

    // ---------------- P3: tile t1, rows 64-127 (aw x bvo) -----------------
#pragma unroll
    for (int i = 0; i < 4; ++i)
      aw[i] = *(const bf16x8*)(bufA1 + (arow + 64 + i * 16) * BK + cc);
    if (s1 < NT) STAGE_B(s1);
    SBAR();
    __builtin_amdgcn_s_setprio(1);
#pragma unroll
    for (int i = 0; i < 4; ++i)
#pragma unroll
      for (int j = 0; j < 4; ++j)
        acc[4 + i][j] = __builtin_amdgcn_mfma_f32_16x16x32_bf16(aw[i], bvo[j],
                                                                acc[4 + i][j],
                                                                0, 0, 0);
    __builtin_amdgcn_s_setprio(0);
    KEEP4(bve);                              // bve regs stay distinct from bvo
    KEEP4(av);
    KEEP4(aw);
    if (g < NG - 2)       asm volatile("s_waitcnt vmcnt(8)" ::: "memory");
    else if (g == NG - 2) asm volatile("s_waitcnt vmcnt(4)" ::: "memory");
    SBAR();
  }

  // ---------------- epilogue: out = alpha*acc + bias ------------------------
  float ax = fmaxf(__uint_as_float(sc[0]), 1e-12f);
  float aw_ = fmaxf(__uint_as_float(sc[1]), 1e-12f);
  float alpha = (ax * aw_) / 7225344.0f;     // amax_x*amax_w / 2688^2

  const int orow = (lane >> 4) * 4;          // C/D: col=lane&15, row=(lane>>4)*4+reg
  const int ocol = lane & 15;
#pragma unroll
  for (int ai = 0; ai < 8; ++ai) {
#pragma unroll
    for (int j = 0; j < 4; ++j) {
      int col = tn0 + wn * 64 + j * 16 + ocol;
      float bvv = bias[col];
#pragma unroll
      for (int rr = 0; rr < 4; ++rr) {
        int row = tm0 + wm * 128 + ai * 16 + orow + rr;
        C[(size_t)row * N + col] = alpha * acc[ai][j][rr] + bvv;
      }
    }
  }
#undef STAGE_A
#undef STAGE_B
}

// ---------------------------------------------------------------------------

extern "C" void kernel_launch(void* const* d_in, const int* in_sizes, int n_in,
                              void* d_out, int out_size, void* d_ws, size_t ws_size,
                              hipStream_t stream) {
  const float* x = (const float*)d_in[0];
  const float* w = (const float*)d_in[1];
  const float* bias = (const float*)d_in[2];
  float* out = (float*)d_out;

  const int N = in_sizes[2];
  const int K = in_sizes[1] / N;
  const int M = in_sizes[0] / K;

  unsigned char* ws = (unsigned char*)d_ws;
  unsigned* sc = (unsigned*)ws;
  u16* dx = (u16*)(ws + 256);
  u16* dw = (u16*)(ws + 256 + (size_t)M * K * sizeof(u16));

  hipMemsetAsync(sc, 0, 8, stream);

  nvfp4_amax_kernel<<<dim3(1024, 2), 256, 0, stream>>>(x, w, sc, M * K / 4,
                                                       N * K / 4);

  int nbx = M * K / 16, nbw = N * K / 16;
  nvfp4_quant_kernel<<<(nbx + 255) / 256, 256, 0, stream>>>(x, dx, sc, 0, nbx);
  nvfp4_quant_kernel<<<(nbw + 255) / 256, 256, 0, stream>>>(w, dw, sc, 1, nbw);

  nvfp4_gemm_kernel<<<dim3((M / BM) * (N / BN)), 512, 0, stream>>>(
      dx, dw, bias, sc, out, M, N, K);
}

// Round 9
// 196.966 us; speedup vs baseline: 1.1136x; 1.0075x over previous
//
#include <hip/hip_runtime.h>
#include <hip/hip_bf16.h>

// NVFP4 dynamic linear: x[2,2048,4096] f32, w[4096,4096] f32, bias[4096] -> out f32
// M=4096, N=4096, K=4096.
//
// amax -> fused coalesced quant/dequant (x & w in one launch) to bf16
// (exact: e2m1 code x e4m3 scale fits bf16; products accumulate exactly in
// fp32 MFMA) -> 256x256 bf16 MFMA GEMM (round-8 structure, unchanged:
// ring-4 LDS, BK=32, 2-tile groups, counted vmcnt(8), T1/T2/T5).
//
// ws: [0,8) amax bits | [256, +32MB) dx bf16 | [+32MB) dw bf16

typedef unsigned short u16;
typedef __bf16 bf16x8 __attribute__((ext_vector_type(8)));
typedef float f32x4 __attribute__((ext_vector_type(4)));
typedef unsigned short u16x8 __attribute__((ext_vector_type(8)));

#define GLD_LDS(gsrc, ldst)                                                     \
  __builtin_amdgcn_global_load_lds(                                             \
      (const __attribute__((address_space(1))) void*)(gsrc),                    \
      (__attribute__((address_space(3))) void*)(ldst), 16, 0, 0)

#define SBAR()                                                                  \
  do {                                                                          \
    asm volatile("" ::: "memory");                                              \
    __builtin_amdgcn_s_barrier();                                               \
    asm volatile("" ::: "memory");                                              \
  } while (0)

#define KEEP4(S) asm volatile("" ::"v"(S[0]), "v"(S[1]), "v"(S[2]), "v"(S[3]))

// ---------------- rounding helpers (bit-exact vs numpy RTNE) -----------------

__device__ __forceinline__ float round_e4m3(float v) {
  if (v < 0.015625f) {                        // subnormal grid, step 2^-9
    return rintf(v * 512.0f) * 0.001953125f;
  }
  unsigned b = __float_as_uint(v);
  unsigned e = (b >> 23) & 0xFFu;
  float step = __uint_as_float((e - 3u) << 23); // 2^(e-127-3)
  return rintf(v / step) * step;
}

__device__ __forceinline__ float round_e2m1(float v) {
  float a = fabsf(v);
  float step = (a < 2.0f) ? 0.5f : ((a < 4.0f) ? 1.0f : 2.0f);
  float q = fminf(rintf(a / step) * step, 6.0f);
  return copysignf(q, v);
}

// ---------------- kernel 1: global amax of |x| and |w| ----------------------

__global__ void nvfp4_amax_kernel(const float* __restrict__ x,
                                  const float* __restrict__ w,
                                  unsigned* __restrict__ sc, int nx4, int nw4) {
  const float4* src = blockIdx.y ? (const float4*)w : (const float4*)x;
  int n4 = blockIdx.y ? nw4 : nx4;
  float m = 0.f;
  for (int i = blockIdx.x * blockDim.x + threadIdx.x; i < n4;
       i += gridDim.x * blockDim.x) {
    float4 v = src[i];
    m = fmaxf(m, fmaxf(fmaxf(fabsf(v.x), fabsf(v.y)),
                       fmaxf(fabsf(v.z), fabsf(v.w))));
  }
#pragma unroll
  for (int off = 32; off; off >>= 1) m = fmaxf(m, __shfl_down(m, off));
  __shared__ float red[4];
  if ((threadIdx.x & 63) == 0) red[threadIdx.x >> 6] = m;
  __syncthreads();
  if (threadIdx.x == 0) {
    m = fmaxf(fmaxf(red[0], red[1]), fmaxf(red[2], red[3]));
    atomicMax(&sc[blockIdx.y], __float_as_uint(m));
  }
}

// ------------- kernel 2: fused coalesced quantize->dequantize ---------------
// lane i owns ONE float4 (16B, coalesced). An NVFP4 16-elem block = 4
// consecutive lanes (aligned quad); block amax via 4-lane shfl_xor reduce.
// Output: 4 bf16 (8B) per lane, coalesced. x occupies blocks [0, nx4/256),
// w the rest (nx4 % 256 == 0 so no mixed block).

__global__ void nvfp4_quant_kernel(const float* __restrict__ x,
                                   const float* __restrict__ w,
                                   u16* __restrict__ dx, u16* __restrict__ dw,
                                   const unsigned* __restrict__ sc,
                                   int nx4, int nw4) {
  int g = blockIdx.x * blockDim.x + threadIdx.x;   // global float4 index
  const float* src; u16* dst; int which, i4;
  if (g < nx4) { src = x; dst = dx; which = 0; i4 = g; }
  else {
    i4 = g - nx4; if (i4 >= nw4) return;
    src = w; dst = dw; which = 1;
  }
  float4 v = ((const float4*)src)[i4];

  float m = fmaxf(fmaxf(fabsf(v.x), fabsf(v.y)), fmaxf(fabsf(v.z), fabsf(v.w)));
  m = fmaxf(m, __shfl_xor(m, 1));                  // 4-lane group = 16-elem block
  m = fmaxf(m, __shfl_xor(m, 2));

  float amax = fmaxf(__uint_as_float(sc[which]), 1e-12f);
  float gs = 2688.0f / amax;
  float sf = round_e4m3((m * gs) / 6.0f);          // same op order as reference
  float sfs = fmaxf(sf, 1e-12f);
  float r = gs / sfs;

  ushort4 o;
  o.x = (u16)(__float_as_uint(round_e2m1(v.x * r) * sf) >> 16);
  o.y = (u16)(__float_as_uint(round_e2m1(v.y * r) * sf) >> 16);
  o.z = (u16)(__float_as_uint(round_e2m1(v.z * r) * sf) >> 16);
  o.w = (u16)(__float_as_uint(round_e2m1(v.w * r) * sf) >> 16);
  ((ushort4*)dst)[i4] = o;                         // 8B coalesced
}

// ---------------- kernel 4: 256x256 bf16 GEMM (round-8, unchanged) ---------
// 512 threads = 8 waves (2M x 4N), per-wave 128x64 = acc[8][4]. BK=32.
// Group = 2 K-tiles = 4 phases; ring-4 LDS; counted vmcnt(8) twice/group;
// fragment sets av/aw/bve/bvo with >=2-phase rewrite gaps.

#define BM 256
#define BN 256
#define BK 32

__global__ __launch_bounds__(512, 2) void nvfp4_gemm_kernel(
    const u16* __restrict__ A,   // dx [M][K]
    const u16* __restrict__ B,   // dw [N][K]
    const float* __restrict__ bias, const unsigned* __restrict__ sc,
    float* __restrict__ C, int M, int N, int K) {
  __shared__ u16 lA[4][BM * BK];
  __shared__ u16 lB[4][BN * BK];

  const int tid = threadIdx.x;
  const int lane = tid & 63;
  const int wv = tid >> 6;
  const int wm = wv >> 2;        // 0..1
  const int wn = wv & 3;         // 0..3

  // T1: XCD-aware swizzle (256 blocks, 8 XCDs x 32; 4x8 tile region per XCD)
  const int bid = blockIdx.x;
  const int xcd = bid & 7, loc = bid >> 3;
  const int tm0 = ((xcd & 3) * 4 + (loc & 3)) * BM;
  const int tn0 = ((xcd >> 2) * 8 + (loc >> 2)) * BN;

  // ---- staging addressing (pre-swizzled global source, linear LDS dest) ----
  const int srow = tid >> 2;                 // 0..127
  const int skey = (srow >> 1) & 3;
  const int scol = ((tid & 3) ^ skey) * 8;   // swizzled 8-elem slot
  const u16* gA0 = A + (size_t)(tm0 + srow) * K + scol;
  const u16* gA1 = A + (size_t)(tm0 + 128 + srow) * K + scol;
  const u16* gB0 = B + (size_t)(tn0 + srow) * K + scol;
  const u16* gB1 = B + (size_t)(tn0 + 128 + srow) * K + scol;
  const int ld0 = tid * 8;
  const int ld1 = tid * 8 + 4096;

#define STAGE_A(tt)                                                             \
  do {                                                                          \
    int _b = (tt) & 3;                                                          \
    GLD_LDS(gA0 + (size_t)(tt) * BK, &lA[_b][ld0]);                             \
    GLD_LDS(gA1 + (size_t)(tt) * BK, &lA[_b][ld1]);                             \
  } while (0)
#define STAGE_B(tt)                                                             \
  do {                                                                          \
    int _b = (tt) & 3;                                                          \
    GLD_LDS(gB0 + (size_t)(tt) * BK, &lB[_b][ld0]);                             \
    GLD_LDS(gB1 + (size_t)(tt) * BK, &lB[_b][ld1]);                             \
  } while (0)

  // ---- fragment addressing (T2 swizzle on read side, same involution) ------
  const int rb = lane & 15;
  const int cc = (((lane >> 4) ^ ((rb >> 1) & 3)) << 3);
  const int arow = wm * 128 + rb;            // + ih*64 + i*16
  const int brow = wn * 64 + rb;             // + j*16

  f32x4 acc[8][4] = {};
  const int NT = K / BK;                     // 128
  const int NG = NT / 2;                     // 64 groups of 2 tiles

  // prologue: stage tiles 0,1,2 (12 loads); vmcnt(8) -> tile 0 resident
  STAGE_A(0); STAGE_B(0);
  STAGE_A(1); STAGE_B(1);
  STAGE_A(2); STAGE_B(2);
  asm volatile("s_waitcnt vmcnt(8)" ::: "memory");
  SBAR();

  bf16x8 av[4], aw[4], bve[4], bvo[4];

  for (int g = 0; g < NG; ++g) {
    const int t0 = 2 * g, t1 = 2 * g + 1;
    const int s0 = 2 * g + 3, s1 = 2 * g + 4;  // tiles staged this group
    const u16* bufA0 = lA[t0 & 3];
    const u16* bufB0 = lB[t0 & 3];
    const u16* bufA1 = lA[t1 & 3];
    const u16* bufB1 = lB[t1 & 3];

    // ---------------- P0: tile t0, rows 0-63 (av x bve) -------------------
#pragma unroll
    for (int j = 0; j < 4; ++j)
      bve[j] = *(const bf16x8*)(bufB0 + (brow + j * 16) * BK + cc);
#pragma unroll
    for (int i = 0; i < 4; ++i)
      av[i] = *(const bf16x8*)(bufA0 + (arow + i * 16) * BK + cc);
    if (s0 < NT) STAGE_A(s0);
    SBAR();
    __builtin_amdgcn_s_setprio(1);
#pragma unroll
    for (int i = 0; i < 4; ++i)
#pragma unroll
      for (int j = 0; j < 4; ++j)
        acc[i][j] = __builtin_amdgcn_mfma_f32_16x16x32_bf16(av[i], bve[j],
                                                            acc[i][j], 0, 0, 0);
    __builtin_amdgcn_s_setprio(0);
    SBAR();

    // ---------------- P1: tile t0, rows 64-127 (aw x bve) -----------------
#pragma unroll
    for (int i = 0; i < 4; ++i)
      aw[i] = *(const bf16x8*)(bufA0 + (arow + 64 + i * 16) * BK + cc);
    if (s0 < NT) STAGE_B(s0);
    SBAR();
    __builtin_amdgcn_s_setprio(1);
#pragma unroll
    for (int i = 0; i < 4; ++i)
#pragma unroll
      for (int j = 0; j < 4; ++j)
        acc[4 + i][j] = __builtin_amdgcn_mfma_f32_16x16x32_bf16(aw[i], bve[j],
                                                                acc[4 + i][j],
                                                                0, 0, 0);
    __builtin_amdgcn_s_setprio(0);
    KEEP4(av);
    if (g < NG - 1) asm volatile("s_waitcnt vmcnt(8)" ::: "memory");
    else            asm volatile("s_waitcnt vmcnt(0)" ::: "memory");
    SBAR();

    // ---------------- P2: tile t1, rows 0-63 (av x bvo) -------------------
#pragma unroll
    for (int j = 0; j < 4; ++j)
      bvo[j] = *(const bf16x8*)(bufB1 + (brow + j * 16) * BK + cc);
#pragma unroll
    for (int i = 0; i < 4; ++i)
      av[i] = *(const bf16x8*)(bufA1 + (arow + i * 16) * BK + cc);
    if (s1 < NT) STAGE_A(s1);
    SBAR();
    __builtin_amdgcn_s_setprio(1);
#pragma unroll
    for (int i = 0; i < 4; ++i)
#pragma unroll
      for (int j = 0; j < 4; ++j)
        acc[i][j] = __builtin_amdgcn_mfma_f32_16x16x32_bf16(av[i], bvo[j],
                                                            acc[i][j], 0, 0, 0);
    __builtin_amdgcn_s_setprio(0);
    SBAR();

    // ---------------- P3: tile t1, rows 64-127 (aw x bvo) -----------------
#pragma unroll
    for (int i = 0; i < 4; ++i)
      aw[i] = *(const bf16x8*)(bufA1 + (arow + 64 + i * 16) * BK + cc);
    if (s1 < NT) STAGE_B(s1);
    SBAR();
    __builtin_amdgcn_s_setprio(1);
#pragma unroll
    for (int i = 0; i < 4; ++i)
#pragma unroll
      for (int j = 0; j < 4; ++j)
        acc[4 + i][j] = __builtin_amdgcn_mfma_f32_16x16x32_bf16(aw[i], bvo[j],
                                                                acc[4 + i][j],
                                                                0, 0, 0);
    __builtin_amdgcn_s_setprio(0);
    KEEP4(bve);
    KEEP4(av);
    KEEP4(aw);
    if (g < NG - 2)       asm volatile("s_waitcnt vmcnt(8)" ::: "memory");
    else if (g == NG - 2) asm volatile("s_waitcnt vmcnt(4)" ::: "memory");
    SBAR();
  }

  // ---------------- epilogue: out = alpha*acc + bias ------------------------
  float ax = fmaxf(__uint_as_float(sc[0]), 1e-12f);
  float aw_ = fmaxf(__uint_as_float(sc[1]), 1e-12f);
  float alpha = (ax * aw_) / 7225344.0f;     // amax_x*amax_w / 2688^2

  const int orow = (lane >> 4) * 4;          // C/D: col=lane&15, row=(lane>>4)*4+reg
  const int ocol = lane & 15;
#pragma unroll
  for (int ai = 0; ai < 8; ++ai) {
#pragma unroll
    for (int j = 0; j < 4; ++j) {
      int col = tn0 + wn * 64 + j * 16 + ocol;
      float bvv = bias[col];
#pragma unroll
      for (int rr = 0; rr < 4; ++rr) {
        int row = tm0 + wm * 128 + ai * 16 + orow + rr;
        C[(size_t)row * N + col] = alpha * acc[ai][j][rr] + bvv;
      }
    }
  }
#undef STAGE_A
#undef STAGE_B
}

// ---------------------------------------------------------------------------

extern "C" void kernel_launch(void* const* d_in, const int* in_sizes, int n_in,
                              void* d_out, int out_size, void* d_ws, size_t ws_size,
                              hipStream_t stream) {
  const float* x = (const float*)d_in[0];
  const float* w = (const float*)d_in[1];
  const float* bias = (const float*)d_in[2];
  float* out = (float*)d_out;

  const int N = in_sizes[2];
  const int K = in_sizes[1] / N;
  const int M = in_sizes[0] / K;

  unsigned char* ws = (unsigned char*)d_ws;
  unsigned* sc = (unsigned*)ws;
  u16* dx = (u16*)(ws + 256);
  u16* dw = (u16*)(ws + 256 + (size_t)M * K * sizeof(u16));

  hipMemsetAsync(sc, 0, 8, stream);

  const int nx4 = M * K / 4, nw4 = N * K / 4;
  nvfp4_amax_kernel<<<dim3(1024, 2), 256, 0, stream>>>(x, w, sc, nx4, nw4);

  nvfp4_quant_kernel<<<(nx4 + nw4 + 255) / 256, 256, 0, stream>>>(
      x, w, dx, dw, sc, nx4, nw4);

  nvfp4_gemm_kernel<<<dim3((M / BM) * (N / BN)), 512, 0, stream>>>(
      dx, dw, bias, sc, out, M, N, K);
}